// Round 11
// baseline (3249.524 us; speedup 1.0000x reference)
//
#include <hip/hip_runtime.h>
#include <math.h>

#ifndef M_PI
#define M_PI 3.14159265358979323846
#endif

#define NXx   360
#define NXY   (NXx*NXx)
#define NTRc  32
#define NMEASc 256
#define NSTEPSc 640
#define NBCc  15
#define PADc  73
#define NVc   214

#define BROWS 45
#define NBANDS 8
#define NBLK  (NTRc*NBANDS)     // 256 blocks == 256 CUs
#define NTHREADS 1024
#define NG    (NXx/4)           // 90 groups/row
#define LDSROWS 49
#define LDSFLOATS (2*LDSROWS*NXx)
#define NSLOT 4
#define HALO_PER (NSLOT*4*NXx)  // 4 slots x 4 rows x 360

#define C2f   1.3333334f
#define C3f  (-0.083333336f)
#define ADX2  0.11111111f
#define DT2f  0.04f
#define DTf   0.2f
#define DXf   0.6f

typedef float f32x4 __attribute__((ext_vector_type(4)));

// ---- system-coherent (sc0 sc1) transport (proven R7): coherence-point ops,
// no wbl2/inv fences needed.
__device__ __forceinline__ void store4_sys(float* p, float4 v) {
    f32x4 vv; vv.x = v.x; vv.y = v.y; vv.z = v.z; vv.w = v.w;
    asm volatile("global_store_dwordx4 %0, %1, off sc0 sc1" :: "v"(p), "v"(vv) : "memory");
}
__device__ __forceinline__ void storei_sys(int* p, int v) {
    asm volatile("global_store_dword %0, %1, off sc0 sc1" :: "v"(p), "v"(v) : "memory");
}
__device__ __forceinline__ int loadi_sys(const int* p) {
    int r;
    asm volatile("global_load_dword %0, %1, off sc0 sc1\n\ts_waitcnt vmcnt(0)"
                 : "=&v"(r) : "v"(p) : "memory");
    return r;
}
__device__ __forceinline__ void drain_vm() {
    asm volatile("s_waitcnt vmcnt(0)" ::: "memory");
}

// batched 180-group pull: issue all sc0sc1 loads, ONE waitcnt, then LDS writes.
// (R10 post-mortem: per-load embedded vmcnt(0) serialized 3 MALL round trips.)
#define PULL180(SB, DB, LANE) { \
    f32x4 d0, d1, d2; d2 = 0.f; \
    bool third = (LANE) < 52; \
    asm volatile("global_load_dwordx4 %0, %1, off sc0 sc1" : "=&v"(d0) : "v"((SB) + 4*(LANE)) : "memory"); \
    asm volatile("global_load_dwordx4 %0, %1, off sc0 sc1" : "=&v"(d1) : "v"((SB) + 4*((LANE)+64)) : "memory"); \
    if (third) { asm volatile("global_load_dwordx4 %0, %1, off sc0 sc1" : "=&v"(d2) : "v"((SB) + 4*((LANE)+128)) : "memory"); } \
    asm volatile("s_waitcnt vmcnt(0)" ::: "memory"); \
    *(f32x4*)((DB) + 4*(LANE)) = d0; \
    *(f32x4*)((DB) + 4*((LANE)+64)) = d1; \
    if (third) { *(f32x4*)((DB) + 4*((LANE)+128)) = d2; } \
}

__global__ void velmin_kernel(const float* __restrict__ v, float* __restrict__ velmin) {
    __shared__ float s[256];
    float m = 1.5f;
    for (int i = threadIdx.x; i < NVc*NVc; i += 256) m = fminf(m, v[i]);
    s[threadIdx.x] = m;
    __syncthreads();
    for (int o = 128; o > 0; o >>= 1) {
        if (threadIdx.x < o) s[threadIdx.x] = fminf(s[threadIdx.x], s[threadIdx.x+o]);
        __syncthreads();
    }
    if (threadIdx.x == 0) *velmin = s[0];
}

__global__ void coef_kernel(const float* __restrict__ v, const float* __restrict__ velmin_p,
                            float* __restrict__ alpha, float* __restrict__ kap) {
    int idx = blockIdx.x*256 + threadIdx.x;
    if (idx >= NXY) return;
    int i = idx / NXx, j = idx - i*NXx;
    float vc = 1.5f;
    if (i >= PADc && i < PADc+NVc && j >= PADc && j < PADc+NVc)
        vc = v[(i-PADc)*NVc + (j-PADc)];
    float v2 = vc*vc;
    float al = v2 * ADX2;
    float velmin = *velmin_p;
    const float a = (float)((NBCc-1)*0.6);
    float ks = 3.0f*velmin*9.2103405f/(2.0f*a);
    float damp = 0.0f;
    int k = -1;
    if (j >= NXx-NBCc)      k = j-(NXx-NBCc);
    else if (j < NBCc)      k = NBCc-1-j;
    else if (i >= NXx-NBCc) k = i-(NXx-NBCc);
    else if (i < NBCc)      k = NBCc-1-i;
    if (k >= 0) { float r = (float)k*DXf/a; damp = ks*r*r; }
    alpha[idx] = al;
    kap[idx]   = damp*DTf;
}

__global__ void beta_kernel(const float* __restrict__ v, const int* __restrict__ in_inds,
                            float* __restrict__ beta) {
    int tr = threadIdx.x;
    if (tr >= NTRc) return;
    int idx = in_inds[tr];
    int i = idx / NXx, j = idx - i*NXx;
    float vc = 1.5f;
    if (i >= PADc && i < PADc+NVc && j >= PADc && j < PADc+NVc)
        vc = v[(i-PADc)*NVc + (j-PADc)];
    beta[tr] = DT2f*vc*vc;
}

// One barrier per step. Roles (concurrent within a step):
//  tid<360  : edge rows 0,1,43,44 -> nxt + halo publish -> drain -> lane0
//             signals LDS counter -> falls through to strip work
//  tid<720  : 5-row strips (rows 2..41), alpha/kap streamed from global
//  720..809 : flat row 42
//  832..895 : poll up flag -> batched pull -> nxt rows 0,1
//  896..959 : poll dn flag -> batched pull -> nxt rows 47,48
//  tid 960  : spin LDS counter==6 edge waves -> publish flag (sc0sc1)
//  tid<256  : measurement gather for field t (reads settled cur)
__global__ __launch_bounds__(NTHREADS, 4) void persist_kernel(
    const float* __restrict__ alpha, const float* __restrict__ kap,
    const float* __restrict__ beta, const float* __restrict__ src,
    const int* __restrict__ meas_inds, const int* __restrict__ in_inds,
    int* flags, float* haloG, float* __restrict__ out)
{
    extern __shared__ float lds[];
    unsigned* cnt = (unsigned*)(lds + LDSFLOATS);
    const int tid  = threadIdx.x;
    const int b    = blockIdx.x;
    const int tr   = b >> 3, band = b & 7;
    const int band0 = band*BROWS;
    const int up = (tr<<3) | ((band+7)&7);
    const int dn = (tr<<3) | ((band+1)&7);

    float* buf0 = lds;
    float* buf1 = lds + LDSROWS*NXx;

    for (int i = tid; i < LDSFLOATS; i += NTHREADS) lds[i] = 0.0f;
    if (tid == 0) *cnt = 0u;

    const float betaV = beta[tr];
    const int sCell = in_inds[tr];
    const int sr = sCell/NXx, scc = sCell - sr*NXx;
    const int sb = sr - band0;
    const int sq = scc >> 2, sqc = scc & 3;

    // ---- edge role (tid < 360): one group, rows {0,1,43,44} ----
    const bool isEdgeT = (tid < 360);
    int eCi = 0, eL = 0, eR = 0, eH = 0, eQ = -1;
    float4 eA = make_float4(0,0,0,0), eK = eA;
    if (isEdgeT) {
        int kk = tid/NG, jg = tid - kk*NG;
        int rowG = (kk < 2) ? kk : (41 + kk);          // 0,1,43,44
        int ldsR = rowG + 2;                           // 2,3,45,46
        eCi = ldsR*NG + jg;
        eL  = eCi - jg + ((jg==0) ? NG-1 : jg-1);
        eR  = eCi - jg + ((jg==NG-1) ? 0 : jg+1);
        eH  = kk*NXx + jg*4;
        int gi = (band0 + rowG)*NXx + jg*4;
        eA = *(const float4*)(alpha + gi);
        eK = *(const float4*)(kap + gi);
        eQ = (sb == rowG && sq == jg) ? sqc : -1;
    }

    // ---- strip role (tid < 720): rows 2+5s .. 6+5s ----
    const bool isStripT = (tid < 720);
    int sBase = 0, sLo = 0, sRo = 0, sQk = -1;
    const float* aP = alpha; const float* kP = kap;
    if (isStripT) {
        int ss = tid/NG, jg = tid - ss*NG;
        sBase = (4 + 5*ss)*NG + jg;
        sLo = (jg==0) ? NG-1 : -1;
        sRo = (jg==NG-1) ? -(NG-1) : 1;
        aP = alpha + (band0 + 2 + 5*ss)*NXx + jg*4;
        kP = kap   + (band0 + 2 + 5*ss)*NXx + jg*4;
        sQk = (sb >= 2+5*ss && sb < 7+5*ss && sq == jg) ? (sb - 2 - 5*ss) : -1;
    }

    // ---- flat row 42 (720 <= tid < 810) ----
    const bool isFlatT = (tid >= 720 && tid < 810);
    int fCi = 0, fL = 0, fR = 0, fQ = -1;
    const float* aPf = alpha; const float* kPf = kap;
    if (isFlatT) {
        int jg = tid - 720;
        fCi = 44*NG + jg;
        fL  = fCi - jg + ((jg==0) ? NG-1 : jg-1);
        fR  = fCi - jg + ((jg==NG-1) ? 0 : jg+1);
        aPf = alpha + (band0 + 42)*NXx + jg*4;
        kPf = kap   + (band0 + 42)*NXx + jg*4;
        fQ = (sb == 42 && sq == jg) ? sqc : -1;
    }

    // ---- measurement role (tid < 256) ----
    bool mOwn = false; int mOff = 0;
    float* outP = out;
    if (tid < NMEASc) {
        int mi = meas_inds[tid]; int row = mi/NXx, col = mi - row*NXx;
        if (row >= band0 && row < band0+BROWS) {
            mOwn = true; mOff = (row-band0+2)*NXx + col;
            outP = out + ((size_t)tr*NSTEPSc)*NMEASc + tid;
        }
    }

    float* myHalo = haloG + (size_t)b*HALO_PER;
    float* upHalo = haloG + (size_t)up*HALO_PER;
    float* dnHalo = haloG + (size_t)dn*HALO_PER;

    __syncthreads();

#define CELLMATH(Cv,U1,D1,U2,D2,Lv,Rv,Pp,AA,KK,QQ) \
    float4 po; \
    { float lap = C2f*(U1.x+D1.x+Lv.w+Cv.y) + C3f*(U2.x+D2.x+Lv.z+Cv.z); \
      float t1v = 2.0f + 2.0f*(-2.5f)*AA.x - KK.x; float t0v = 1.0f - KK.x; \
      po.x = AA.x*lap + t1v*Cv.x - t0v*Pp.x; } \
    { float lap = C2f*(U1.y+D1.y+Cv.x+Cv.z) + C3f*(U2.y+D2.y+Lv.w+Cv.w); \
      float t1v = 2.0f + 2.0f*(-2.5f)*AA.y - KK.y; float t0v = 1.0f - KK.y; \
      po.y = AA.y*lap + t1v*Cv.y - t0v*Pp.y; } \
    { float lap = C2f*(U1.z+D1.z+Cv.y+Cv.w) + C3f*(U2.z+D2.z+Cv.x+Rv.x); \
      float t1v = 2.0f + 2.0f*(-2.5f)*AA.z - KK.z; float t0v = 1.0f - KK.z; \
      po.z = AA.z*lap + t1v*Cv.z - t0v*Pp.z; } \
    { float lap = C2f*(U1.w+D1.w+Cv.z+Rv.x) + C3f*(U2.w+D2.w+Cv.y+Rv.y); \
      float t1v = 2.0f + 2.0f*(-2.5f)*AA.w - KK.w; float t0v = 1.0f - KK.w; \
      po.w = AA.w*lap + t1v*Cv.w - t0v*Pp.w; } \
    if (QQ >= 0) { float add = betaV*srcT; \
        po.x += (QQ==0)?add:0.0f; po.y += (QQ==1)?add:0.0f; \
        po.z += (QQ==2)?add:0.0f; po.w += (QQ==3)?add:0.0f; }

    for (int t = 0; t < NSTEPSc; ++t) {
        const int slot = t & 1;
        const int hsOff = ((t+1) & 3)*4*NXx;
        float* cur = (slot == 0) ? buf0 : buf1;
        float* nxt = (slot == 0) ? buf1 : buf0;
        const float4* cur4 = (const float4*)cur;
        float4* nxt4 = (float4*)nxt;
        const float srcT = src[t];

        // gather for field t (settled in cur by the end-of-step barrier)
        if (mOwn && t > 0) outP[(size_t)(t-1)*NMEASc] = cur[mOff];

        // ---- edge rows + halo publish + wave-level signal ----
        if (isEdgeT) {
            float4 Cv = cur4[eCi], Lv = cur4[eL], Rv = cur4[eR];
            float4 U1 = cur4[eCi-NG], D1 = cur4[eCi+NG];
            float4 U2 = cur4[eCi-2*NG], D2 = cur4[eCi+2*NG];
            float4 Pp = nxt4[eCi];
            CELLMATH(Cv,U1,D1,U2,D2,Lv,Rv,Pp,eA,eK,eQ)
            nxt4[eCi] = po;
            store4_sys(myHalo + hsOff + eH, po);
            drain_vm();          // wave-level: all halo stores of this wave acked
            if ((tid & 63) == 0)
                __hip_atomic_fetch_add(cnt, 1u, __ATOMIC_RELAXED, __HIP_MEMORY_SCOPE_WORKGROUP);
        }

        // ---- concurrent: strips | flat | pulls | flag publisher ----
        if (isStripT) {
            int ci = sBase;
            float4 cm2 = cur4[ci-2*NG], cm1 = cur4[ci-NG], cc0 = cur4[ci];
            float4 cp1 = cur4[ci+NG],  cp2 = cur4[ci+2*NG];
#pragma unroll
            for (int k = 0; k < 5; ++k) {
                float4 Al = *(const float4*)(aP + k*NXx);
                float4 Kp = *(const float4*)(kP + k*NXx);
                float4 Lv = cur4[ci + sLo], Rv = cur4[ci + sRo];
                float4 Pp = nxt4[ci];
                CELLMATH(cc0,cm1,cp1,cm2,cp2,Lv,Rv,Pp,Al,Kp,(k==sQk?sqc:-1))
                nxt4[ci] = po;
                cm2 = cm1; cm1 = cc0; cc0 = cp1; cp1 = cp2;
                if (k < 4) cp2 = cur4[ci + 3*NG];
                ci += NG;
            }
        } else if (isFlatT) {
            float4 Al = *(const float4*)(aPf);
            float4 Kp = *(const float4*)(kPf);
            float4 Cv = cur4[fCi], Lv = cur4[fL], Rv = cur4[fR];
            float4 U1 = cur4[fCi-NG], D1 = cur4[fCi+NG];
            float4 U2 = cur4[fCi-2*NG], D2 = cur4[fCi+2*NG];
            float4 Pp = nxt4[fCi];
            CELLMATH(Cv,U1,D1,U2,D2,Lv,Rv,Pp,Al,Kp,fQ)
            nxt4[fCi] = po;
        } else if (tid >= 832 && tid < 896) {
            if (tid == 832) {
                int g = 0;
                while (loadi_sys(flags + up) <= t)
                    { __builtin_amdgcn_s_sleep(1); if (++g > 2000000) break; }
            }
            int lane = tid - 832;
            const float* sbp = upHalo + hsOff + 2*NXx;   // up rows 2,3 -> our rows 0,1
            PULL180(sbp, nxt, lane)
        } else if (tid >= 896 && tid < 960) {
            if (tid == 896) {
                int g = 0;
                while (loadi_sys(flags + dn) <= t)
                    { __builtin_amdgcn_s_sleep(1); if (++g > 2000000) break; }
            }
            int lane = tid - 896;
            const float* sbp = dnHalo + hsOff;           // dn rows 0,1 -> our rows 47,48
            PULL180(sbp, nxt + 47*NXx, lane)
        } else if (tid == 960) {
            unsigned target = 6u*(unsigned)(t+1);
            int g = 0;
            while (__hip_atomic_load(cnt, __ATOMIC_RELAXED, __HIP_MEMORY_SCOPE_WORKGROUP) < target)
                { __builtin_amdgcn_s_sleep(1); if (++g > 20000000) break; }
            storei_sys(flags + b, t + 1);   // halos already at coherence point
        }

        __syncthreads();   // nxt complete (edges+strips+halo pulls) -> next step
    }
    // final gather: field 640 is in buf0 (t=639: slot=1 -> nxt=buf0)
    if (mOwn) outP[(size_t)(NSTEPSc-1)*NMEASc] = buf0[mOff];
#undef CELLMATH
}

extern "C" void kernel_launch(void* const* d_in, const int* in_sizes, int n_in,
                              void* d_out, int out_size, void* d_ws, size_t ws_size,
                              hipStream_t stream) {
    const float* v = (const float*)d_in[0];
    float* out = (float*)d_out;

    float* haloG  = (float*)d_ws;                       // NBLK*HALO_PER (16B-aligned)
    float* alpha  = haloG + (size_t)NBLK*HALO_PER;      // 129600
    float* kap    = alpha + NXY;                        // 129600
    float* beta   = kap + NXY;                          // 32
    float* velmin = beta + NTRc;                        // 1
    float* src_d  = velmin + 1;                         // 640
    int*   meas_d = (int*)(src_d + NSTEPSc);            // 256
    int*   in_d   = meas_d + NMEASc;                    // 32
    int*   flags  = in_d + NTRc;                        // 256

    static int   h_tab[NMEASc + NTRc];
    static float h_src[NSTEPSc];
    {
        const double step = 2.0*M_PI/256.0;
        for (int k = 0; k < NMEASc; ++k) {
            double th = (double)k * step;
            int ti0 = (int)floor(160.0*cos(th) + 179.5);
            int ti1 = (int)floor(160.0*sin(th) + 179.5);
            h_tab[k] = NXx*ti0 + ti1;
        }
        for (int r = 0; r < NTRc; ++r) h_tab[NMEASc + r] = h_tab[r*(NMEASc/NTRc)];
        for (int t = 0; t < NSTEPSc; ++t) {
            double tt = (double)t * 0.2;
            double d  = tt - 3.2;
            double e  = exp(-(d*d) / 288.0);
            double s  = sin(6.283185307179586 * tt);
            h_src[t] = (float)(e * s);
        }
    }
    (void)hipMemcpyAsync(meas_d, h_tab, sizeof(int)*(NMEASc+NTRc), hipMemcpyHostToDevice, stream);
    (void)hipMemcpyAsync(src_d, h_src, sizeof(float)*NSTEPSc, hipMemcpyHostToDevice, stream);
    (void)hipMemsetAsync(haloG, 0, sizeof(float)*(size_t)NBLK*HALO_PER, stream);
    (void)hipMemsetAsync(flags, 0, sizeof(int)*NBLK, stream);

    velmin_kernel<<<1, 256, 0, stream>>>(v, velmin);
    coef_kernel<<<(NXY+255)/256, 256, 0, stream>>>(v, velmin, alpha, kap);
    beta_kernel<<<1, 64, 0, stream>>>(v, in_d, beta);

    (void)hipFuncSetAttribute((const void*)persist_kernel,
                        hipFuncAttributeMaxDynamicSharedMemorySize, (LDSFLOATS+4)*4);

    persist_kernel<<<NBLK, NTHREADS, (LDSFLOATS+4)*4, stream>>>(
        alpha, kap, beta, src_d, meas_d, in_d, flags, haloG, out);
}

// Round 12
// 2427.740 us; speedup vs baseline: 1.3385x; 1.3385x over previous
//
#include <hip/hip_runtime.h>
#include <math.h>

#ifndef M_PI
#define M_PI 3.14159265358979323846
#endif

#define NXx   360
#define NXY   (NXx*NXx)
#define NTRc  32
#define NMEASc 256
#define NSTEPSc 640
#define NBCc  15
#define PADc  73
#define NVc   214

#define BROWS 45
#define NBANDS 8
#define NBLK  (NTRc*NBANDS)     // 256 blocks == 256 CUs
#define NTHREADS 1024
#define NG    (NXx/4)           // 90 groups/row
#define LDSROWS 49
#define LDSFLOATS (2*LDSROWS*NXx)
#define NSLOT 4
#define HALO_PER (NSLOT*4*NXx)  // 4 slots x 4 rows x 360
#define NPAIR 1800              // 20 pair-rows (2..41) x 90
#define NFLAT 90                // row 42

#define C2f   1.3333334f
#define C3f  (-0.083333336f)
#define ADX2  0.11111111f
#define DT2f  0.04f
#define DTf   0.2f
#define DXf   0.6f

typedef float f32x4 __attribute__((ext_vector_type(4)));

// ---- system-coherent (sc0 sc1) transport (proven R7): coherence-point ops,
// no wbl2/inv fences needed.
__device__ __forceinline__ void store4_sys(float* p, float4 v) {
    f32x4 vv; vv.x = v.x; vv.y = v.y; vv.z = v.z; vv.w = v.w;
    asm volatile("global_store_dwordx4 %0, %1, off sc0 sc1" :: "v"(p), "v"(vv) : "memory");
}
__device__ __forceinline__ float4 load4_sys(const float* p) {
    f32x4 r;
    asm volatile("global_load_dwordx4 %0, %1, off sc0 sc1\n\ts_waitcnt vmcnt(0)"
                 : "=&v"(r) : "v"(p) : "memory");
    return make_float4(r.x, r.y, r.z, r.w);
}
__device__ __forceinline__ void storei_sys(int* p, int v) {
    asm volatile("global_store_dword %0, %1, off sc0 sc1" :: "v"(p), "v"(v) : "memory");
}
__device__ __forceinline__ int loadi_sys(const int* p) {
    int r;
    asm volatile("global_load_dword %0, %1, off sc0 sc1\n\ts_waitcnt vmcnt(0)"
                 : "=&v"(r) : "v"(p) : "memory");
    return r;
}
__device__ __forceinline__ void drain_vm() {
    asm volatile("s_waitcnt vmcnt(0)" ::: "memory");
}

__global__ void velmin_kernel(const float* __restrict__ v, float* __restrict__ velmin) {
    __shared__ float s[256];
    float m = 1.5f;
    for (int i = threadIdx.x; i < NVc*NVc; i += 256) m = fminf(m, v[i]);
    s[threadIdx.x] = m;
    __syncthreads();
    for (int o = 128; o > 0; o >>= 1) {
        if (threadIdx.x < o) s[threadIdx.x] = fminf(s[threadIdx.x], s[threadIdx.x+o]);
        __syncthreads();
    }
    if (threadIdx.x == 0) *velmin = s[0];
}

__global__ void coef_kernel(const float* __restrict__ v, const float* __restrict__ velmin_p,
                            float* __restrict__ alpha, float* __restrict__ kap) {
    int idx = blockIdx.x*256 + threadIdx.x;
    if (idx >= NXY) return;
    int i = idx / NXx, j = idx - i*NXx;
    float vc = 1.5f;
    if (i >= PADc && i < PADc+NVc && j >= PADc && j < PADc+NVc)
        vc = v[(i-PADc)*NVc + (j-PADc)];
    float v2 = vc*vc;
    float al = v2 * ADX2;
    float velmin = *velmin_p;
    const float a = (float)((NBCc-1)*0.6);
    float ks = 3.0f*velmin*9.2103405f/(2.0f*a);
    float damp = 0.0f;
    int k = -1;
    if (j >= NXx-NBCc)      k = j-(NXx-NBCc);
    else if (j < NBCc)      k = NBCc-1-j;
    else if (i >= NXx-NBCc) k = i-(NXx-NBCc);
    else if (i < NBCc)      k = NBCc-1-i;
    if (k >= 0) { float r = (float)k*DXf/a; damp = ks*r*r; }
    alpha[idx] = al;
    kap[idx]   = damp*DTf;
}

__global__ void beta_kernel(const float* __restrict__ v, const int* __restrict__ in_inds,
                            float* __restrict__ beta) {
    int tr = threadIdx.x;
    if (tr >= NTRc) return;
    int idx = in_inds[tr];
    int i = idx / NXx, j = idx - i*NXx;
    float vc = 1.5f;
    if (i >= PADc && i < PADc+NVc && j >= PADc && j < PADc+NVc)
        vc = v[(i-PADc)*NVc + (j-PADc)];
    beta[tr] = DT2f*vc*vc;
}

// R7's exact schedule (proven 2250us) with 2-row-paired interior compute:
//  phase 1: tid<360 edge rows {0,1,43,44} -> nxt + halo publish -> drain
//  barrier; tid0 flag publish (sc0sc1)
//  phase 2: 1800 row-pairs (rows 2..41) + 90 flat (row 42); <=2 items/thread;
//           pairs share the 6-row column window: 14 b128 per 2 groups (was 18)
//  phase 3: poll neighbor flags (tid0/tid64) — flag is ~3us old by now
//  barrier
//  phase 4: tid<360 pull halos (one load4_sys each, parallel round trip)
//  phase 5: gather; barrier.
__global__ __launch_bounds__(NTHREADS, 4) void persist_kernel(
    const float* __restrict__ alpha, const float* __restrict__ kap,
    const float* __restrict__ beta, const float* __restrict__ src,
    const int* __restrict__ meas_inds, const int* __restrict__ in_inds,
    int* flags, float* haloG, float* __restrict__ out)
{
    extern __shared__ float lds[];
    const int tid  = threadIdx.x;
    const int b    = blockIdx.x;
    const int tr   = b >> 3, band = b & 7;
    const int band0 = band*BROWS;
    const int up = (tr<<3) | ((band+7)&7);
    const int dn = (tr<<3) | ((band+1)&7);

    float* buf0 = lds;
    float* buf1 = lds + LDSROWS*NXx;

    for (int i = tid; i < LDSFLOATS; i += NTHREADS) lds[i] = 0.0f;

    const float betaV = beta[tr];
    const int sCell = in_inds[tr];
    const int sr = sCell/NXx, scc = sCell - sr*NXx;
    const int sb = sr - band0;
    const int sq = scc >> 2, sqc = scc & 3;

    // ---- edge role (tid < 360): one group, rows {0,1,43,44} ----
    const bool isEdgeT = (tid < 360);
    int eCi = 0, eL = 0, eR = 0, eH = 0, eQ = -1;
    float4 eA = make_float4(0,0,0,0), eK = eA;
    if (isEdgeT) {
        int kk = tid/NG, jg = tid - kk*NG;
        int rowG = (kk < 2) ? kk : (41 + kk);          // 0,1,43,44
        eCi = (rowG + 2)*NG + jg;
        eL  = eCi - jg + ((jg==0) ? NG-1 : jg-1);
        eR  = eCi - jg + ((jg==NG-1) ? 0 : jg+1);
        eH  = kk*NXx + jg*4;
        int gi = (band0 + rowG)*NXx + jg*4;
        eA = *(const float4*)(alpha + gi);
        eK = *(const float4*)(kap + gi);
        eQ = (sb == rowG && sq == jg) ? sqc : -1;
    }

    // ---- pair item 1 (all threads): pair index tid ----
    int ci1, lo1, ro1, q1a = -1, q1b = -1;
    float4 A1a, K1a, A1b, K1b;
    {
        int pr = 2 + 2*(tid/NG), jg = tid - NG*(tid/NG);
        ci1 = (pr + 2)*NG + jg;
        lo1 = (jg==0) ? NG-1 : -1;
        ro1 = (jg==NG-1) ? -(NG-1) : 1;
        int gi = (band0 + pr)*NXx + jg*4;
        A1a = *(const float4*)(alpha + gi);       K1a = *(const float4*)(kap + gi);
        A1b = *(const float4*)(alpha + gi + NXx); K1b = *(const float4*)(kap + gi + NXx);
        q1a = (sb == pr   && sq == jg) ? sqc : -1;
        q1b = (sb == pr+1 && sq == jg) ? sqc : -1;
    }

    // ---- item 2: pair tid+1024 (tid<776) or flat row 42 (776<=tid<866) ----
    const bool has2p = (tid < NPAIR - 1024);           // 776
    const bool has2f = (!has2p && tid < NPAIR - 1024 + NFLAT);  // 776..865
    int ci2 = 0, lo2 = 0, ro2 = 0, q2a = -1, q2b = -1;
    float4 A2a = make_float4(0,0,0,0), K2a = A2a, A2b = A2a, K2b = A2a;
    if (has2p) {
        int p2 = tid + 1024;
        int pr = 2 + 2*(p2/NG), jg = p2 - NG*(p2/NG);
        ci2 = (pr + 2)*NG + jg;
        lo2 = (jg==0) ? NG-1 : -1;
        ro2 = (jg==NG-1) ? -(NG-1) : 1;
        int gi = (band0 + pr)*NXx + jg*4;
        A2a = *(const float4*)(alpha + gi);       K2a = *(const float4*)(kap + gi);
        A2b = *(const float4*)(alpha + gi + NXx); K2b = *(const float4*)(kap + gi + NXx);
        q2a = (sb == pr   && sq == jg) ? sqc : -1;
        q2b = (sb == pr+1 && sq == jg) ? sqc : -1;
    } else if (has2f) {
        int jg = tid - 776;
        ci2 = 44*NG + jg;                                // LDS row 44 = field row 42
        lo2 = (jg==0) ? NG-1 : -1;
        ro2 = (jg==NG-1) ? -(NG-1) : 1;
        int gi = (band0 + 42)*NXx + jg*4;
        A2a = *(const float4*)(alpha + gi); K2a = *(const float4*)(kap + gi);
        q2a = (sb == 42 && sq == jg) ? sqc : -1;
    }

    // ---- measurement role (tid < 256) ----
    bool mOwn = false; int mOff = 0;
    float* outP = out;
    if (tid < NMEASc) {
        int mi = meas_inds[tid]; int row = mi/NXx, col = mi - row*NXx;
        if (row >= band0 && row < band0+BROWS) {
            mOwn = true; mOff = (row-band0+2)*NXx + col;
            outP = out + ((size_t)tr*NSTEPSc)*NMEASc + tid;
        }
    }

    float* myHalo = haloG + (size_t)b*HALO_PER;
    float* upHalo = haloG + (size_t)up*HALO_PER;
    float* dnHalo = haloG + (size_t)dn*HALO_PER;

    __syncthreads();

#define CELLMATH(Cv,U1,D1,U2,D2,Lv,Rv,Pp,AA,KK,QQ) \
    float4 po; \
    { float lap = C2f*(U1.x+D1.x+Lv.w+Cv.y) + C3f*(U2.x+D2.x+Lv.z+Cv.z); \
      float t1v = 2.0f + 2.0f*(-2.5f)*AA.x - KK.x; float t0v = 1.0f - KK.x; \
      po.x = AA.x*lap + t1v*Cv.x - t0v*Pp.x; } \
    { float lap = C2f*(U1.y+D1.y+Cv.x+Cv.z) + C3f*(U2.y+D2.y+Lv.w+Cv.w); \
      float t1v = 2.0f + 2.0f*(-2.5f)*AA.y - KK.y; float t0v = 1.0f - KK.y; \
      po.y = AA.y*lap + t1v*Cv.y - t0v*Pp.y; } \
    { float lap = C2f*(U1.z+D1.z+Cv.y+Cv.w) + C3f*(U2.z+D2.z+Cv.x+Rv.x); \
      float t1v = 2.0f + 2.0f*(-2.5f)*AA.z - KK.z; float t0v = 1.0f - KK.z; \
      po.z = AA.z*lap + t1v*Cv.z - t0v*Pp.z; } \
    { float lap = C2f*(U1.w+D1.w+Cv.z+Rv.x) + C3f*(U2.w+D2.w+Cv.y+Rv.y); \
      float t1v = 2.0f + 2.0f*(-2.5f)*AA.w - KK.w; float t0v = 1.0f - KK.w; \
      po.w = AA.w*lap + t1v*Cv.w - t0v*Pp.w; } \
    if (QQ >= 0) { float add = betaV*srcT; \
        po.x += (QQ==0)?add:0.0f; po.y += (QQ==1)?add:0.0f; \
        po.z += (QQ==2)?add:0.0f; po.w += (QQ==3)?add:0.0f; }

// 2-row pair: 12 reads + 2 writes for 2 output groups (6-row column window)
#define PAIR_COMPUTE(CI,LO,RO,Aa,Ka,Ab,Kb,Qa,Qb) { \
    float4 cm2 = cur4[CI-2*NG], cm1 = cur4[CI-NG], c0 = cur4[CI]; \
    float4 c1 = cur4[CI+NG], c2 = cur4[CI+2*NG], c3 = cur4[CI+3*NG]; \
    float4 Lv0 = cur4[CI+LO],    Rv0 = cur4[CI+RO]; \
    float4 Lv1 = cur4[CI+NG+LO], Rv1 = cur4[CI+NG+RO]; \
    float4 Pp0 = nxt4[CI], Pp1 = nxt4[CI+NG]; \
    { CELLMATH(c0,cm1,c1,cm2,c2,Lv0,Rv0,Pp0,Aa,Ka,Qa) nxt4[CI] = po; } \
    { CELLMATH(c1,c0,c2,cm1,c3,Lv1,Rv1,Pp1,Ab,Kb,Qb) nxt4[CI+NG] = po; } \
}

    for (int t = 0; t < NSTEPSc; ++t) {
        const int slot = t & 1;
        const int hsOff = ((t+1) & 3)*4*NXx;
        float* cur = (slot == 0) ? buf0 : buf1;
        float* nxt = (slot == 0) ? buf1 : buf0;
        const float4* cur4 = (const float4*)cur;
        float4* nxt4 = (float4*)nxt;
        const float srcT = src[t];

        // ---- phase 1: edge rows + halo publish ----
        if (isEdgeT) {
            float4 Cv = cur4[eCi], Lv = cur4[eL], Rv = cur4[eR];
            float4 U1 = cur4[eCi-NG], D1 = cur4[eCi+NG];
            float4 U2 = cur4[eCi-2*NG], D2 = cur4[eCi+2*NG];
            float4 Pp = nxt4[eCi];
            CELLMATH(Cv,U1,D1,U2,D2,Lv,Rv,Pp,eA,eK,eQ)
            nxt4[eCi] = po;
            store4_sys(myHalo + hsOff + eH, po);
            drain_vm();          // halo stores at coherence point before barrier
        }
        __syncthreads();
        if (tid == 0) storei_sys(flags + b, t + 1);

        // ---- phase 2: paired interior (rows 2..41) + flat row 42 ----
        PAIR_COMPUTE(ci1, lo1, ro1, A1a, K1a, A1b, K1b, q1a, q1b)
        if (has2p) {
            PAIR_COMPUTE(ci2, lo2, ro2, A2a, K2a, A2b, K2b, q2a, q2b)
        } else if (has2f) {
            float4 Cv = cur4[ci2], Lv = cur4[ci2+lo2], Rv = cur4[ci2+ro2];
            float4 U1 = cur4[ci2-NG], D1 = cur4[ci2+NG];
            float4 U2 = cur4[ci2-2*NG], D2 = cur4[ci2+2*NG];
            float4 Pp = nxt4[ci2];
            CELLMATH(Cv,U1,D1,U2,D2,Lv,Rv,Pp,A2a,K2a,q2a)
            nxt4[ci2] = po;
        }

        // ---- phase 3: wait for neighbors' field t+1 (flag is ~3us old) ----
        if (tid == 0) {
            int g = 0;
            while (loadi_sys(flags + up) <= t)
                { __builtin_amdgcn_s_sleep(1); if (++g > 2000000) break; }
        }
        if (tid == 64) {
            int g = 0;
            while (loadi_sys(flags + dn) <= t)
                { __builtin_amdgcn_s_sleep(1); if (++g > 2000000) break; }
        }
        __syncthreads();

        // ---- phase 4: pull halos of field t+1 into nxt rows {0,1,47,48} ----
        if (tid < 360) {
            int rr = tid / NG, jq = tid - rr*NG;
            const float* sp = (rr < 2) ? (upHalo + hsOff + (2+rr)*NXx + jq*4)
                                       : (dnHalo + hsOff + (rr-2)*NXx + jq*4);
            float4 hv = load4_sys(sp);
            int ldr = (rr < 2) ? rr : (45 + rr);    // 0,1,47,48
            *(float4*)(nxt + ldr*NXx + jq*4) = hv;
        }

        // ---- phase 5: receiver gather for step t (field t+1, from LDS) ----
        if (mOwn) outP[(size_t)t*NMEASc] = nxt[mOff];

        __syncthreads();
    }
#undef PAIR_COMPUTE
#undef CELLMATH
}

extern "C" void kernel_launch(void* const* d_in, const int* in_sizes, int n_in,
                              void* d_out, int out_size, void* d_ws, size_t ws_size,
                              hipStream_t stream) {
    const float* v = (const float*)d_in[0];
    float* out = (float*)d_out;

    float* haloG  = (float*)d_ws;                       // NBLK*HALO_PER (16B-aligned)
    float* alpha  = haloG + (size_t)NBLK*HALO_PER;      // 129600
    float* kap    = alpha + NXY;                        // 129600
    float* beta   = kap + NXY;                          // 32
    float* velmin = beta + NTRc;                        // 1
    float* src_d  = velmin + 1;                         // 640
    int*   meas_d = (int*)(src_d + NSTEPSc);            // 256
    int*   in_d   = meas_d + NMEASc;                    // 32
    int*   flags  = in_d + NTRc;                        // 256

    static int   h_tab[NMEASc + NTRc];
    static float h_src[NSTEPSc];
    {
        const double step = 2.0*M_PI/256.0;
        for (int k = 0; k < NMEASc; ++k) {
            double th = (double)k * step;
            int ti0 = (int)floor(160.0*cos(th) + 179.5);
            int ti1 = (int)floor(160.0*sin(th) + 179.5);
            h_tab[k] = NXx*ti0 + ti1;
        }
        for (int r = 0; r < NTRc; ++r) h_tab[NMEASc + r] = h_tab[r*(NMEASc/NTRc)];
        for (int t = 0; t < NSTEPSc; ++t) {
            double tt = (double)t * 0.2;
            double d  = tt - 3.2;
            double e  = exp(-(d*d) / 288.0);
            double s  = sin(6.283185307179586 * tt);
            h_src[t] = (float)(e * s);
        }
    }
    (void)hipMemcpyAsync(meas_d, h_tab, sizeof(int)*(NMEASc+NTRc), hipMemcpyHostToDevice, stream);
    (void)hipMemcpyAsync(src_d, h_src, sizeof(float)*NSTEPSc, hipMemcpyHostToDevice, stream);
    (void)hipMemsetAsync(haloG, 0, sizeof(float)*(size_t)NBLK*HALO_PER, stream);
    (void)hipMemsetAsync(flags, 0, sizeof(int)*NBLK, stream);

    velmin_kernel<<<1, 256, 0, stream>>>(v, velmin);
    coef_kernel<<<(NXY+255)/256, 256, 0, stream>>>(v, velmin, alpha, kap);
    beta_kernel<<<1, 64, 0, stream>>>(v, in_d, beta);

    (void)hipFuncSetAttribute((const void*)persist_kernel,
                        hipFuncAttributeMaxDynamicSharedMemorySize, LDSFLOATS*4);

    persist_kernel<<<NBLK, NTHREADS, LDSFLOATS*4, stream>>>(
        alpha, kap, beta, src_d, meas_d, in_d, flags, haloG, out);
}